// Round 2
// baseline (441.035 us; speedup 1.0000x reference)
//
#include <hip/hip_runtime.h>

#define CUTOFF 1.6f
#define BLOCK 256
#define EPT 8
#define EPB (BLOCK * EPT)

#define ST_INV 0ull
#define ST_AGG (1ull << 62)
#define ST_PRE (2ull << 62)

struct f3 { float x, y, z; };

// Fused single-pass: passthrough copies + mask + block scan + decoupled
// lookback + stable compacted scatter. Last block writes n_sr.
__global__ void __launch_bounds__(BLOCK) k_main(
    const float* __restrict__ Rij, const int* __restrict__ idx_i,
    const int* __restrict__ idx_j, float* __restrict__ out,
    unsigned long long* __restrict__ ts, int* __restrict__ nsr,
    long E, int nb)
{
  long b = blockIdx.x;
  int t = threadIdx.x;
  int lane = t & 63, wid = t >> 6;
  long base = b * (long)EPB + (long)t * EPT;

  float rr[24];
  int ii[EPT], jj[EPT];
  unsigned m = 0;
  int cnt = 0;

  if (base < E) {  // E % 8 == 0 -> thread has all 8 edges or none
    // Rij: 24 consecutive floats per thread, 96B-aligned -> 6x float4
    const float4* rp4 = (const float4*)(Rij + base * 3);
    float4* op4 = (float4*)(out + base * 3);
#pragma unroll
    for (int q = 0; q < 6; ++q) {
      float4 v = rp4[q];
      op4[q] = v;
      rr[q * 4 + 0] = v.x; rr[q * 4 + 1] = v.y;
      rr[q * 4 + 2] = v.z; rr[q * 4 + 3] = v.w;
    }
    const int4* ip = (const int4*)(idx_i + base);
    const int4* jp = (const int4*)(idx_j + base);
    int4 ia = ip[0], ib = ip[1], ja = jp[0], jb = jp[1];
    ii[0] = ia.x; ii[1] = ia.y; ii[2] = ia.z; ii[3] = ia.w;
    ii[4] = ib.x; ii[5] = ib.y; ii[6] = ib.z; ii[7] = ib.w;
    jj[0] = ja.x; jj[1] = ja.y; jj[2] = ja.z; jj[3] = ja.w;
    jj[4] = jb.x; jj[5] = jb.y; jj[6] = jb.z; jj[7] = jb.w;
#pragma unroll
    for (int k = 0; k < EPT; ++k) {
      float x = rr[3 * k], y = rr[3 * k + 1], z = rr[3 * k + 2];
      float s = sqrtf(x * x + y * y + z * z);
      if (s <= CUTOFF) { m |= 1u << k; ++cnt; }
    }
  }

  // block scan of per-thread counts
  int sv = cnt;
#pragma unroll
  for (int d = 1; d < 64; d <<= 1) {
    int n = __shfl_up(sv, d, 64);
    if (lane >= d) sv += n;
  }
  __shared__ int wsum[BLOCK / 64];
  __shared__ int sh_excl;
  if (lane == 63) wsum[wid] = sv;
  __syncthreads();
  int woff = 0, bsum = 0;
#pragma unroll
  for (int w = 0; w < BLOCK / 64; ++w) {
    int s = wsum[w];
    if (w < wid) woff += s;
    bsum += s;
  }
  int texcl = woff + sv - cnt;  // thread's exclusive offset within block

  // wave 0: publish aggregate, lookback, publish inclusive prefix
  if (wid == 0) {
    if (lane == 0 && b > 0) {
      __hip_atomic_store(&ts[b], (unsigned long long)bsum | ST_AGG,
                         __ATOMIC_RELAXED, __HIP_MEMORY_SCOPE_AGENT);
    }
    long excl = 0;
    if (b > 0) {
      int pred = (int)b - 1;
      for (;;) {
        int i = pred - lane;
        unsigned long long s =
            (i >= 0) ? __hip_atomic_load(&ts[i], __ATOMIC_RELAXED,
                                         __HIP_MEMORY_SCOPE_AGENT)
                     : 0ull;
        unsigned st = (unsigned)(s >> 62);
        int val = (int)(s & 0xFFFFFFFFull);
        unsigned long long invm = __ballot(st == 0u);
        unsigned long long prfm = __ballot(st == 2u);
        int mm = invm ? (__ffsll((long long)invm) - 1) : 64;
        int pp = prfm ? (__ffsll((long long)prfm) - 1) : 64;
        if (pp < mm) {
          int c = (lane <= pp) ? val : 0;
#pragma unroll
          for (int d = 32; d; d >>= 1) c += __shfl_down(c, d, 64);
          excl += c;  // lane 0 holds the true sum
          break;
        } else if (mm > 0) {
          int c = (lane < mm) ? val : 0;
#pragma unroll
          for (int d = 32; d; d >>= 1) c += __shfl_down(c, d, 64);
          excl += c;
          pred -= mm;
        } else {
          __builtin_amdgcn_s_sleep(1);
        }
      }
    }
    if (lane == 0) {
      long inc = excl + bsum;
      __hip_atomic_store(&ts[b], (unsigned long long)inc | ST_PRE,
                         __ATOMIC_RELAXED, __HIP_MEMORY_SCOPE_AGENT);
      sh_excl = (int)excl;
      if (b == (long)nb - 1) {
        nsr[0] = (int)inc;
        out[10 * E] = (float)inc;
      }
    }
  }

  // overlap: idx passthrough stores while wave 0 spins
  if (base < E) {
    float4 fi0 = make_float4((float)ii[0], (float)ii[1], (float)ii[2], (float)ii[3]);
    float4 fi1 = make_float4((float)ii[4], (float)ii[5], (float)ii[6], (float)ii[7]);
    float4 fj0 = make_float4((float)jj[0], (float)jj[1], (float)jj[2], (float)jj[3]);
    float4 fj1 = make_float4((float)jj[4], (float)jj[5], (float)jj[6], (float)jj[7]);
    *(float4*)(out + 3 * E + base) = fi0;
    *(float4*)(out + 3 * E + base + 4) = fi1;
    *(float4*)(out + 4 * E + base) = fj0;
    *(float4*)(out + 4 * E + base + 4) = fj1;
  }
  __syncthreads();

  long pos = (long)sh_excl + texcl;
  if (base < E && m) {
    f3* srp = (f3*)(out + 5 * E);
    float* oi = out + 8 * E;
    float* oj = out + 9 * E;
#pragma unroll
    for (int k = 0; k < EPT; ++k) {
      if (m & (1u << k)) {
        f3 v{rr[3 * k], rr[3 * k + 1], rr[3 * k + 2]};
        srp[pos] = v;
        oi[pos] = (float)ii[k];
        oj[pos] = (float)jj[k];
        ++pos;
      }
    }
  }
}

// fill padding region [n_sr, E): Rij_sr rows = 0, idx_sr = -1.
__global__ void __launch_bounds__(256) k_fill(
    float* __restrict__ out, const int* __restrict__ nsr, long E)
{
  long n = *nsr;
  long stride = (long)gridDim.x * blockDim.x;
  f3* sr = (f3*)(out + 5 * E);
  float* oi = out + 8 * E;
  float* oj = out + 9 * E;
  for (long i = n + (long)blockIdx.x * blockDim.x + threadIdx.x; i < E;
       i += stride) {
    f3 z{0.f, 0.f, 0.f};
    sr[i] = z;
    oi[i] = -1.0f;
    oj[i] = -1.0f;
  }
}

extern "C" void kernel_launch(void* const* d_in, const int* in_sizes, int n_in,
                              void* d_out, int out_size, void* d_ws,
                              size_t ws_size, hipStream_t stream)
{
  const float* Rij = (const float*)d_in[0];
  const int* idx_i = (const int*)d_in[1];
  const int* idx_j = (const int*)d_in[2];
  long E = (long)in_sizes[1];
  float* out = (float*)d_out;

  int nb = (int)((E + EPB - 1) / EPB);
  unsigned long long* ts = (unsigned long long*)d_ws;  // nb words
  int* nsr = (int*)(ts + nb);                          // 1 int

  // tile states must be INVALID at kernel start (ws is poisoned, and must be
  // re-zeroed deterministically for every graph replay)
  hipMemsetAsync(d_ws, 0, (size_t)nb * 8, stream);

  k_main<<<nb, BLOCK, 0, stream>>>(Rij, idx_i, idx_j, out, ts, nsr, E, nb);
  k_fill<<<2048, 256, 0, stream>>>(out, nsr, E);
}